// Round 3
// baseline (123.717 us; speedup 1.0000x reference)
//
#include <hip/hip_runtime.h>
#include <math.h>

#define NPH 8
#define NLUT 2048
#define SCALE ((float)(NLUT - 1))   // 2047 interpolation intervals over x in [0,1]

typedef float f32x4 __attribute__((ext_vector_type(4)));

// LUT lives in a module-scope device array: NO workspace usage (poison is
// unconditional anyway — measured R1 — but this keeps us independent of d_ws).
// Entries 0..NLUT (2049 valid, padded to 2050 for float4 staging), (P, Q) pairs.
__device__ __align__(16) float2 g_lut[NLUT + 2];

// Full QSVT evaluation with the off-diagonal term sigma passed explicitly.
// f_alg(x, sigma) is a polynomial in sigma, so evaluating at +/-sigma splits
// even/odd parts: f = P(x) + sigma*Q(x).
__device__ __forceinline__ float qsvt_eval(float x, float sig,
                                           const float* cph, const float* sph) {
    float v0r, v0i, v1r, v1i;
    __sincosf(0.5f * x, &v1r, &v0r);   // [cos(x/2), sin(x/2)]
    v0i = 0.0f; v1i = 0.0f;
#pragma unroll
    for (int k = 0; k < NPH; ++k) {
        const float c = cph[k], sn = sph[k];
        const float a0r = v0r * c - v0i * sn;
        const float a0i = v0r * sn + v0i * c;
        const float a1r = v1r * c + v1i * sn;
        const float a1i = v1i * c - v1r * sn;
        if (k < NPH - 1) {
            v0r = x * a0r + sig * a1r;
            v0i = x * a0i + sig * a1i;
            v1r = sig * a0r - x * a1r;
            v1i = sig * a0i - x * a1i;
        } else {
            v0r = a0r; v0i = a0i; v1r = a1r; v1i = a1i;
        }
    }
    return (v0r * v0r + v0i * v0i) - (v1r * v1r + v1i * v1i);
}

// Kernel 1: build (P,Q) table into the module-scope device array. ~1 us.
// Arithmetic unchanged from R0/R1 -> bit-identical table.
__global__ void build_lut(const float* __restrict__ phi) {
    const int j = blockIdx.x * blockDim.x + threadIdx.x;
    if (j > NLUT) return;              // entries 0..NLUT inclusive (2049)
    float cph[NPH], sph[NPH];
#pragma unroll
    for (int k = 0; k < NPH; ++k) __sincosf(phi[k], &sph[k], &cph[k]);
    const int jj = (j < NLUT) ? j : (NLUT - 1);  // pad entry NLUT == entry NLUT-1
    float x = (float)jj * (1.0f / SCALE);
    float s = sqrtf(fmaxf(1.0f - x * x, 0.0f));
    if (s < 1e-3f) {            // endpoint x=1: sample at consistent (x~1, s=1e-3)
        s = 1e-3f;              // P,Q smooth -> sampling offset ~5e-7 in x negligible
        x = sqrtf(1.0f - s * s);
    }
    const float fp = qsvt_eval(x,  s, cph, sph);
    const float fm = qsvt_eval(x, -s, cph, sph);
    g_lut[j] = make_float2(0.5f * (fp + fm), (fp - fm) / (2.0f * s));
}

// Bit-identical to R1's interpolation (the R1 dead term was exactly +/-0);
// just without the unfoldable dead FLOPs.
__device__ __forceinline__ float lut_eval(float xin, const float2* __restrict__ lut) {
    const float x = fminf(fmaxf(xin, 0.0f), 1.0f);   // inputs are uniform [0,1)
    const float u = x * SCALE;                        // u in [0, 2047]
    const int i = (int)u;                             // trunc; i <= 2047
    const float fr = u - (float)i;
    const float2 e0 = lut[i];                         // one ds_read2_b64
    const float2 e1 = lut[i + 1];
    const float s = sqrtf(fmaxf(fmaf(-x, x, 1.0f), 0.0f));
    const float p = fmaf(fr, e1.x - e0.x, e0.x);
    const float q = fmaf(fr, e1.y - e0.y, e0.y);
    return fmaf(s, q, p);
}

__device__ __forceinline__ f32x4 eval4(f32x4 v, const float2* __restrict__ lut) {
    f32x4 o;
    o.x = lut_eval(v.x, lut);
    o.y = lut_eval(v.y, lut);
    o.z = lut_eval(v.z, lut);
    o.w = lut_eval(v.w, lut);
    return o;
}

// Kernel 2: stage 16.4 KB LUT in LDS (8 blocks/CU -> full 32-wave occupancy),
// then a gather+FMA grid-stride map, 2x unrolled with paired nontemporal
// loads for MLP=2 per wave.
__global__ __launch_bounds__(256, 8) void qsvt_main(const float* __restrict__ x,
                                                    float* __restrict__ out, int n) {
    __shared__ float2 lut[NLUT + 2];
    {
        const f32x4* __restrict__ src = (const f32x4*)g_lut;
        f32x4* dst = (f32x4*)lut;
        for (int j = threadIdx.x; j < (NLUT + 2) / 2; j += 256) dst[j] = src[j];
    }
    __syncthreads();

    const int n4 = n >> 2;
    const f32x4* __restrict__ x4 = (const f32x4*)x;
    f32x4* __restrict__ o4 = (f32x4*)out;
    const int idx = blockIdx.x * blockDim.x + threadIdx.x;
    const int stride = gridDim.x * blockDim.x;

    // For the bench shape (n4 = 4.19M, stride = 524288) this is exactly 4
    // iterations with has2 always true; guards kept for generality.
    for (int i = idx; i < n4; i += 2 * stride) {
        const int i2 = i + stride;
        const bool has2 = i2 < n4;
        // Issue both independent loads before any dependent use (MLP=2).
        const f32x4 a = __builtin_nontemporal_load(x4 + i);
        const f32x4 b = has2 ? __builtin_nontemporal_load(x4 + i2) : a;
        const f32x4 oa = eval4(a, lut);
        const f32x4 ob = eval4(b, lut);
        __builtin_nontemporal_store(oa, o4 + i);
        if (has2) __builtin_nontemporal_store(ob, o4 + i2);
    }
    const int tail = n & 3;
    if (tail) {
        const int base = n4 << 2;
        if (idx < tail) out[base + idx] = lut_eval(x[base + idx], lut);
    }
}

extern "C" void kernel_launch(void* const* d_in, const int* in_sizes, int n_in,
                              void* d_out, int out_size, void* d_ws, size_t ws_size,
                              hipStream_t stream) {
    const float* x   = (const float*)d_in[0];   // x_chunk [B*CHUNK] fp32
    // d_in[1] = theta: RZ is unit-modulus diagonal -> cannot change <Z>; dead.
    const float* phi = (const float*)d_in[2];   // phi [8] fp32
    float* out = (float*)d_out;
    const int n = in_sizes[0];
    (void)d_ws; (void)ws_size;                  // workspace deliberately UNUSED

    build_lut<<<(NLUT + 1 + 63) / 64, 64, 0, stream>>>(phi);
    // 2048 blocks = 8 blocks/CU (16.4 KB LDS, 32-wave cap) x 256 CUs.
    qsvt_main<<<2048, 256, 0, stream>>>(x, out, n);
}

// Round 4
// 118.498 us; speedup vs baseline: 1.0440x; 1.0440x over previous
//
#include <hip/hip_runtime.h>
#include <math.h>

#define NPH 8
#define NLUT 2048
#define SCALE ((float)(NLUT - 1))   // 2047 interpolation intervals over x in [0,1]

typedef float f32x4 __attribute__((ext_vector_type(4)));

// LUT lives in a module-scope device array: NO workspace usage (poison is
// unconditional — measured R1 — but this keeps us independent of d_ws).
// Entries 0..NLUT (2049 valid, padded to 2050 for float4 staging), (P, Q) pairs.
__device__ __align__(16) float2 g_lut[NLUT + 2];

// Full QSVT evaluation with the off-diagonal term sigma passed explicitly.
// f_alg(x, sigma) is a polynomial in sigma, so evaluating at +/-sigma splits
// even/odd parts: f = P(x) + sigma*Q(x).
__device__ __forceinline__ float qsvt_eval(float x, float sig,
                                           const float* cph, const float* sph) {
    float v0r, v0i, v1r, v1i;
    __sincosf(0.5f * x, &v1r, &v0r);   // [cos(x/2), sin(x/2)]
    v0i = 0.0f; v1i = 0.0f;
#pragma unroll
    for (int k = 0; k < NPH; ++k) {
        const float c = cph[k], sn = sph[k];
        const float a0r = v0r * c - v0i * sn;
        const float a0i = v0r * sn + v0i * c;
        const float a1r = v1r * c + v1i * sn;
        const float a1i = v1i * c - v1r * sn;
        if (k < NPH - 1) {
            v0r = x * a0r + sig * a1r;
            v0i = x * a0i + sig * a1i;
            v1r = sig * a0r - x * a1r;
            v1i = sig * a0i - x * a1i;
        } else {
            v0r = a0r; v0i = a0i; v1r = a1r; v1i = a1i;
        }
    }
    return (v0r * v0r + v0i * v0i) - (v1r * v1r + v1i * v1i);
}

// Kernel 1: build (P,Q) table into the module-scope device array. ~1.5 us.
// Arithmetic unchanged from R0/R1 -> bit-identical table.
__global__ void build_lut(const float* __restrict__ phi) {
    const int j = blockIdx.x * blockDim.x + threadIdx.x;
    if (j > NLUT) return;              // entries 0..NLUT inclusive (2049)
    float cph[NPH], sph[NPH];
#pragma unroll
    for (int k = 0; k < NPH; ++k) __sincosf(phi[k], &sph[k], &cph[k]);
    const int jj = (j < NLUT) ? j : (NLUT - 1);  // pad entry NLUT == entry NLUT-1
    float x = (float)jj * (1.0f / SCALE);
    float s = sqrtf(fmaxf(1.0f - x * x, 0.0f));
    if (s < 1e-3f) {            // endpoint x=1: sample at consistent (x~1, s=1e-3)
        s = 1e-3f;              // P,Q smooth -> sampling offset ~5e-7 in x negligible
        x = sqrtf(1.0f - s * s);
    }
    const float fp = qsvt_eval(x,  s, cph, sph);
    const float fm = qsvt_eval(x, -s, cph, sph);
    g_lut[j] = make_float2(0.5f * (fp + fm), (fp - fm) / (2.0f * s));
}

// Bit-identical to R1's interpolation.
__device__ __forceinline__ float lut_eval(float xin, const float2* __restrict__ lut) {
    const float x = fminf(fmaxf(xin, 0.0f), 1.0f);   // inputs are uniform [0,1)
    const float u = x * SCALE;                        // u in [0, 2047]
    const int i = (int)u;                             // trunc; i <= 2047
    const float fr = u - (float)i;
    const float2 e0 = lut[i];                         // adjacent pair -> ds_read2_b64
    const float2 e1 = lut[i + 1];
    const float s = sqrtf(fmaxf(fmaf(-x, x, 1.0f), 0.0f));
    const float p = fmaf(fr, e1.x - e0.x, e0.x);
    const float q = fmaf(fr, e1.y - e0.y, e0.y);
    return fmaf(s, q, p);
}

__device__ __forceinline__ f32x4 eval4(f32x4 v, const float2* __restrict__ lut) {
    f32x4 o;
    o.x = lut_eval(v.x, lut);
    o.y = lut_eval(v.y, lut);
    o.z = lut_eval(v.z, lut);
    o.w = lut_eval(v.w, lut);
    return o;
}

// Kernel 2: 16.4 KB LUT in LDS (8 blocks/CU, full 32-wave occupancy).
// Software-pipelined grid-stride map: 32 B (two adjacent float4) per thread
// per iteration; next iteration's loads issue BEFORE current eval (depth-1
// prefetch, MLP=2, contiguous streams, NO nontemporal). First loads issue
// before LDS staging so staging hides under the first HBM miss.
__global__ __launch_bounds__(256, 8) void qsvt_main(const float* __restrict__ x,
                                                    float* __restrict__ out, int n) {
    __shared__ float2 lut[NLUT + 2];

    const int n8 = n >> 3;                       // 32 B chunks
    const f32x4* __restrict__ x4 = (const f32x4*)x;
    f32x4* __restrict__ o4 = (f32x4*)out;
    const int idx = blockIdx.x * blockDim.x + threadIdx.x;
    const int stride = gridDim.x * blockDim.x;

    // Prologue: issue first-iteration loads before touching LDS.
    f32x4 a, b;
    if (idx < n8) {
        a = x4[2 * idx];
        b = x4[2 * idx + 1];
    }

    // Stage LUT (16.4 KB) from L2-resident g_lut while the loads are in flight.
    {
        const f32x4* __restrict__ src = (const f32x4*)g_lut;
        f32x4* dst = (f32x4*)lut;
        for (int j = threadIdx.x; j < (NLUT + 2) / 2; j += 256) dst[j] = src[j];
    }
    __syncthreads();

    // Bench shape: n8 = 2,097,152; stride = 524,288 -> exactly 4 iterations,
    // `more` uniform across the grid each iteration.
    for (int i = idx; i < n8; i += stride) {
        const int inext = i + stride;
        const bool more = inext < n8;
        f32x4 an, bn;
        if (more) {                              // depth-1 prefetch
            an = x4[2 * inext];
            bn = x4[2 * inext + 1];
        }
        o4[2 * i]     = eval4(a, lut);
        o4[2 * i + 1] = eval4(b, lut);
        a = an; b = bn;
    }

    const int tail = n & 7;
    if (tail) {
        const int base = n8 << 3;
        if (idx < tail) out[base + idx] = lut_eval(x[base + idx], lut);
    }
}

extern "C" void kernel_launch(void* const* d_in, const int* in_sizes, int n_in,
                              void* d_out, int out_size, void* d_ws, size_t ws_size,
                              hipStream_t stream) {
    const float* x   = (const float*)d_in[0];   // x_chunk [B*CHUNK] fp32
    // d_in[1] = theta: RZ is unit-modulus diagonal -> cannot change <Z>; dead.
    const float* phi = (const float*)d_in[2];   // phi [8] fp32
    float* out = (float*)d_out;
    const int n = in_sizes[0];
    (void)d_ws; (void)ws_size;                  // workspace deliberately UNUSED

    build_lut<<<(NLUT + 1 + 63) / 64, 64, 0, stream>>>(phi);
    // 2048 blocks = 8 blocks/CU (16.4 KB LDS, 32-wave cap) x 256 CUs.
    qsvt_main<<<2048, 256, 0, stream>>>(x, out, n);
}